// Round 7
// baseline (127.768 us; speedup 1.0000x reference)
//
#include <hip/hip_runtime.h>
#include <math.h>

// Mamba selective scan:
//   u, delta, z : (2, 2048, 1024) f32 ; A : (2048, 16) f32
//   B, C : (2, 16, 1024) f32 ; D, delta_bias : (2048,) f32 ; softplus flag
// Output y : (2, 2048, 1024) f32
//
// v13: BARRIER-FREE single-wave-per-row structure.
//   - 1 wave = 1 row: lane = chunk (64 chunks x CL=16), all 16 n-states
//     held in-lane (x[16]). All LDS strictly wave-private -> zero
//     __syncthreads in the kernel. Waves free-run and overlap phases.
//   - v11 correction form: pass1 = recurrence + y_loc (B+C), stores
//     (y_locD, prefix) in-place; combine = 64-lane scan (6 stages);
//     pass2 = C-only exp2-weighted dot, no recurrence, no shfl_xor.
//   - depth-2 prefetch rings, compile-time ring indices (r6-proven).
//   - NO register cap (r2/r4 lesson). Tripwire: WRITE_SIZE == 16384 KB.
constexpr int Bsz = 2, Dm = 2048, L = 1024, N = 16;
constexpr int CL = 16;          // steps per chunk (per lane)
constexpr int RPB = 4;          // rows per block = waves per block (1 wave/row)
constexpr int TPB = RPB * 64;   // 256
constexpr int ISTR2 = 65;       // float2 stride per step (64 chunks + 1 pad)
constexpr int LROW2 = CL * ISTR2;    // 1040 float2 per row (8.3 KB)
constexpr float LOG2E = 1.4426950408889634f;
constexpr float RLOG2E = 0.6931471805599453f;   // ln 2

#define EXP2(x) __builtin_amdgcn_exp2f(x)

// ---------------------------------------------------------------------------
// Transform B,C into scan layout (chunk length 16), k-contiguous:
//   Bs[b*4096 + i*256 + cg*4 + k] = float4 { B[b][4k+q][cg*16+i] } q=0..3
// Scan lane cg reads k=0..3 at step i -> 4 adjacent float4 (64 B/lane).
// ---------------------------------------------------------------------------
__global__ __launch_bounds__(256) void transform_bc_kernel(
    const float* __restrict__ B_g, const float* __restrict__ C_g,
    float4* __restrict__ Bs, float4* __restrict__ Cs)
{
    const int o = threadIdx.x + 256 * blockIdx.x;   // 4096 float4 per (b, src)
    const int b = blockIdx.y;
    const float* __restrict__ src = blockIdx.z ? C_g : B_g;
    float4* __restrict__ dst = blockIdx.z ? Cs : Bs;
    const int k = o & 3, cg = (o >> 2) & 63, i = o >> 8;
    const int l = cg * CL + i;
    float4 v;
    v.x = src[(size_t)(b * N + 4 * k + 0) * L + l];
    v.y = src[(size_t)(b * N + 4 * k + 1) * L + l];
    v.z = src[(size_t)(b * N + 4 * k + 2) * L + l];
    v.w = src[(size_t)(b * N + 4 * k + 3) * L + l];
    dst[(size_t)b * 4096 + o] = v;
}

// ---------------------------------------------------------------------------
// Scan kernel: 4 waves/block = 4 independent rows. No barriers anywhere.
// ---------------------------------------------------------------------------
template<bool XF>
__global__ __launch_bounds__(TPB) void mamba_scan13_kernel(
    const float* __restrict__ u_g, const float* __restrict__ delta_g,
    const float* __restrict__ A_g,
    const float* __restrict__ B_g, const float* __restrict__ C_g,
    const float4* __restrict__ Bs, const float4* __restrict__ Cs,
    const float* __restrict__ D_g, const float* __restrict__ z_g,
    const float* __restrict__ bias_g, const int* __restrict__ sp_g,
    float* __restrict__ y_g)
{
    __shared__ float2 du_s[RPB * LROW2];  // per-wave slice: (dtp,u) -> (y_locD, prefix) -> y_core

    const int tid = threadIdx.x;
    const int wv = tid >> 6;                   // wave id == local row
    const int lane = tid & 63;
    const int cg = lane;                       // chunk 0..63
    const int row = blockIdx.x * RPB + wv;
    const int b = row >> 11;                   // row / Dm (blocks never straddle)
    const int d = row & (Dm - 1);
    const int sp = sp_g[0];
    const float bias = bias_g[d];
    const int lb = wv * LROW2;                 // wave-private LDS base

    // ---- Phase 0: coalesced load of delta/u -> step-major packed LDS ----
    // Wave-private: no barrier needed before pass 1 (same-wave lgkmcnt).
#pragma unroll
    for (int p = 0; p < 4; ++p) {
        const int l0 = 4 * lane + 256 * p;
        const size_t gb = (size_t)row * L + l0;
        const float4 d4 = *reinterpret_cast<const float4*>(&delta_g[gb]);
        const float4 u4 = *reinterpret_cast<const float4*>(&u_g[gb]);
        const float dv[4] = {d4.x, d4.y, d4.z, d4.w};
        const float uv[4] = {u4.x, u4.y, u4.z, u4.w};
#pragma unroll
        for (int k = 0; k < 4; ++k) {
            const int li = l0 + k;
            const float t = dv[k] + bias;
            // softplus: max(t,0) + ln(1 + 2^(-|t|*log2e))
            const float e = EXP2(-fabsf(t) * LOG2E);
            const float p_ = sp ? (fmaxf(t, 0.f) +
                                   __builtin_amdgcn_logf(1.f + e) * RLOG2E)
                                : t;
            const int a = (li & (CL - 1)) * ISTR2 + (li >> 4);  // [step][chunk]
            du_s[lb + a] = make_float2(p_, uv[k]);
        }
    }

    float A2[16];
#pragma unroll
    for (int g = 0; g < 4; ++g) {
        const float4 a4 = *reinterpret_cast<const float4*>(&A_g[d * N + g * 4]);
        A2[g * 4 + 0] = a4.x * LOG2E; A2[g * 4 + 1] = a4.y * LOG2E;
        A2[g * 4 + 2] = a4.z * LOG2E; A2[g * 4 + 3] = a4.w * LOG2E;
    }
    const size_t base = (size_t)b * 4096 + cg * 4;   // float4 units; step i at +i*256
    const float Dd = D_g[d];

    // ---- Pass 1: chunk-local zero-init recurrence + y_loc (B and C) ----
    float x[16];
#pragma unroll
    for (int n = 0; n < 16; ++n) x[n] = 0.f;
    float ssum = 0.f;

    if (XF) {
        float4 rB[2][4], rC[2][4];                 // depth-2 ring
#pragma unroll
        for (int j = 0; j < 2; ++j)
#pragma unroll
            for (int k = 0; k < 4; ++k) {
                rB[j][k] = Bs[base + j * 256 + k];
                rC[j][k] = Cs[base + j * 256 + k];
            }
#pragma unroll
        for (int i = 0; i < CL; ++i) {
            const float2 du = du_s[lb + i * ISTR2 + cg];
            const float dtp = du.x;
            const float uu = du.y;
            const float dtu = dtp * uu;
            ssum += dtp;
            float bv[16], cv[16];
#pragma unroll
            for (int k = 0; k < 4; ++k) {
                bv[4 * k + 0] = rB[i & 1][k].x; bv[4 * k + 1] = rB[i & 1][k].y;
                bv[4 * k + 2] = rB[i & 1][k].z; bv[4 * k + 3] = rB[i & 1][k].w;
                cv[4 * k + 0] = rC[i & 1][k].x; cv[4 * k + 1] = rC[i & 1][k].y;
                cv[4 * k + 2] = rC[i & 1][k].z; cv[4 * k + 3] = rC[i & 1][k].w;
            }
            if (i + 2 < CL) {
#pragma unroll
                for (int k = 0; k < 4; ++k) {
                    rB[i & 1][k] = Bs[base + (i + 2) * 256 + k];
                    rC[i & 1][k] = Cs[base + (i + 2) * 256 + k];
                }
            }
            float acc = 0.f;
#pragma unroll
            for (int n = 0; n < 16; ++n) {
                const float a = EXP2(dtp * A2[n]);
                x[n] = fmaf(a, x[n], dtu * bv[n]);
                acc = fmaf(x[n], cv[n], acc);
            }
            // in-place overwrite of own slot (read this step, lane-owned)
            du_s[lb + i * ISTR2 + cg] = make_float2(fmaf(uu, Dd, acc), ssum);
        }
    } else {
#pragma unroll 2
        for (int i = 0; i < CL; ++i) {
            const float2 du = du_s[lb + i * ISTR2 + cg];
            const float dtp = du.x;
            const float uu = du.y;
            const float dtu = dtp * uu;
            ssum += dtp;
            const int l = cg * CL + i;
            float bv[16], cv[16];
#pragma unroll
            for (int n = 0; n < 16; ++n) {
                bv[n] = B_g[(size_t)(b * N + n) * L + l];
                cv[n] = C_g[(size_t)(b * N + n) * L + l];
            }
            float acc = 0.f;
#pragma unroll
            for (int n = 0; n < 16; ++n) {
                const float a = EXP2(dtp * A2[n]);
                x[n] = fmaf(a, x[n], dtu * bv[n]);
                acc = fmaf(x[n], cv[n], acc);
            }
            du_s[lb + i * ISTR2 + cg] = make_float2(fmaf(uu, Dd, acc), ssum);
        }
    }

    // ---- Combine: 64-lane inclusive scan of (P, x), then exclusive ----
    float P[16];
#pragma unroll
    for (int n = 0; n < 16; ++n) P[n] = EXP2(A2[n] * ssum);
#pragma unroll
    for (int s = 1; s < 64; s <<= 1) {
        const bool ok = (lane >= s);
#pragma unroll
        for (int n = 0; n < 16; ++n) {
            const float xp = __shfl_up(x[n], s, 64);
            const float Pp = __shfl_up(P[n], s, 64);
            if (ok) {
                x[n] = fmaf(P[n], xp, x[n]);
                P[n] = P[n] * Pp;
            }
        }
    }
#pragma unroll
    for (int n = 0; n < 16; ++n) {
        const float xi = __shfl_up(x[n], 1, 64);
        x[n] = lane ? xi : 0.f;                // x_init for my chunk
    }

    // ---- Pass 2: correction only -- C stream, no recurrence ----
    //   y_i = y_loc_i + sum_n C_in * exp2(A2[n]*prefix_i) * x_init[n]
    if (XF) {
        float4 rC[2][4];
#pragma unroll
        for (int j = 0; j < 2; ++j)
#pragma unroll
            for (int k = 0; k < 4; ++k)
                rC[j][k] = Cs[base + j * 256 + k];
#pragma unroll
        for (int i = 0; i < CL; ++i) {
            const float2 yp = du_s[lb + i * ISTR2 + cg];   // (y_locD, prefix)
            float cv[16];
#pragma unroll
            for (int k = 0; k < 4; ++k) {
                cv[4 * k + 0] = rC[i & 1][k].x; cv[4 * k + 1] = rC[i & 1][k].y;
                cv[4 * k + 2] = rC[i & 1][k].z; cv[4 * k + 3] = rC[i & 1][k].w;
            }
            if (i + 2 < CL) {
#pragma unroll
                for (int k = 0; k < 4; ++k)
                    rC[i & 1][k] = Cs[base + (i + 2) * 256 + k];
            }
            float corr = 0.f;
#pragma unroll
            for (int n = 0; n < 16; ++n) {
                const float pn = EXP2(A2[n] * yp.y);
                corr = fmaf(pn * x[n], cv[n], corr);
            }
            du_s[lb + i * ISTR2 + cg].x = yp.x + corr;     // final y_core
        }
    } else {
#pragma unroll 2
        for (int i = 0; i < CL; ++i) {
            const float2 yp = du_s[lb + i * ISTR2 + cg];
            const int l = cg * CL + i;
            float cv[16];
#pragma unroll
            for (int n = 0; n < 16; ++n)
                cv[n] = C_g[(size_t)(b * N + n) * L + l];
            float corr = 0.f;
#pragma unroll
            for (int n = 0; n < 16; ++n) {
                const float pn = EXP2(A2[n] * yp.y);
                corr = fmaf(pn * x[n], cv[n], corr);
            }
            du_s[lb + i * ISTR2 + cg].x = yp.x + corr;
        }
    }

    // ---- Epilogue: coalesced z read, silu gate, coalesced y store ----
    // Wave-private LDS read-back: no barrier needed (same wave wrote it).
#pragma unroll
    for (int p = 0; p < 4; ++p) {
        const int l0 = 4 * lane + 256 * p;
        const size_t gb = (size_t)row * L + l0;
        const float4 z4 = *reinterpret_cast<const float4*>(&z_g[gb]);
        const float zv[4] = {z4.x, z4.y, z4.z, z4.w};
        float out[4];
#pragma unroll
        for (int k = 0; k < 4; ++k) {
            const int li = l0 + k;
            const float yc = du_s[lb + (li & (CL - 1)) * ISTR2 + (li >> 4)].x;
            const float e = EXP2(-zv[k] * LOG2E);
            const float sig = __builtin_amdgcn_rcpf(1.f + e);
            out[k] = yc * (zv[k] * sig);
        }
        *reinterpret_cast<float4*>(&y_g[gb]) = make_float4(out[0], out[1], out[2], out[3]);
    }
}

extern "C" void kernel_launch(void* const* d_in, const int* in_sizes, int n_in,
                              void* d_out, int out_size, void* d_ws, size_t ws_size,
                              hipStream_t stream) {
    const float* u     = (const float*)d_in[0];
    const float* delta = (const float*)d_in[1];
    const float* A     = (const float*)d_in[2];
    const float* B     = (const float*)d_in[3];
    const float* C     = (const float*)d_in[4];
    const float* D     = (const float*)d_in[5];
    const float* z     = (const float*)d_in[6];
    const float* bias  = (const float*)d_in[7];
    const int*   sp    = (const int*)d_in[8];
    float* y = (float*)d_out;

    const size_t bc_bytes = (size_t)Bsz * 4096 * sizeof(float4);  // 128 KB each
    const bool xf = ws_size >= 2 * bc_bytes;
    float4* Bs = (float4*)d_ws;
    float4* Cs = (float4*)((char*)d_ws + bc_bytes);

    if (xf) {
        transform_bc_kernel<<<dim3(16, Bsz, 2), 256, 0, stream>>>(B, C, Bs, Cs);
        mamba_scan13_kernel<true><<<dim3((Bsz * Dm) / RPB), TPB, 0, stream>>>(
            u, delta, A, B, C, Bs, Cs, D, z, bias, sp, y);
    } else {
        mamba_scan13_kernel<false><<<dim3((Bsz * Dm) / RPB), TPB, 0, stream>>>(
            u, delta, A, B, C, Bs, Cs, D, z, bias, sp, y);
    }
}

// Round 8
// 59.870 us; speedup vs baseline: 2.1341x; 2.1341x over previous
//
#include <hip/hip_runtime.h>
#include <math.h>

// Mamba selective scan:
//   u, delta, z : (2, 2048, 1024) f32 ; A : (2048, 16) f32
//   B, C : (2, 16, 1024) f32 ; D, delta_bias : (2048,) f32 ; softplus flag
// Output y : (2, 2048, 1024) f32
//
// v14 = v12 (60.3 us: 2 waves/row, depth-4 rings, raw builtins) with the
//       combine moved OFF the DS pipe:
//       - P[8] eliminated: decay product is rank-1, P_win[n] =
//         exp2(A2[n] * ss_win) -> scan the SCALAR ssum only.
//       - 32-lane segmented scan via DPP (row_shr:1/2/4/8 + row_bcast:15),
//         VALU pipe, branchless (invalid lanes read 0 = identity).
//       - exclusive shift via row_shr:1 with c==16 -> row_bcast:15 select.
//       DS ops/thread ~190 -> ~75; combine chain ~600cy -> ~150cy; -P regs.
//       NO register cap (r2/r4 lesson). Tripwire: WRITE_SIZE == 16384 KB.
constexpr int Bsz = 2, Dm = 2048, L = 1024, N = 16;
constexpr int CL = 16;          // chunk length (steps per lane)
constexpr int WPR = 2;          // waves per row
constexpr int RPB = 2;          // rows per block
constexpr int TPB = RPB * WPR * 64;  // 256
constexpr int ISTR2 = 65;       // float2 stride per step (64 chunks + 1 pad)
constexpr int LROW2 = CL * ISTR2;    // 1040 float2 per row
constexpr float LOG2E = 1.4426950408889634f;
constexpr float RLOG2E = 0.6931471805599453f;   // ln 2

#define EXP2(x) __builtin_amdgcn_exp2f(x)

// DPP lane-shift on the VALU pipe. Invalid-source lanes get old=0.
// ctrl: 0x111=row_shr:1  0x112=row_shr:2  0x114=row_shr:4  0x118=row_shr:8
//       0x142=row_bcast:15 (lane15->16..31, lane47->48..63)
#define DPPF(CTRL, v) __builtin_bit_cast(float, __builtin_amdgcn_update_dpp( \
        0, __builtin_bit_cast(int, (float)(v)), (CTRL), 0xF, 0xF, false))

// One affine-scan stage over (ss, x[8]) with window-decay exp2(A2[n]*ss).
#define COMBINE_STAGE(CTRL) do {                                          \
    const float ssp_ = DPPF(CTRL, ss);                                    \
    float xp_[8];                                                         \
    _Pragma("unroll") for (int n_ = 0; n_ < 8; ++n_)                      \
        xp_[n_] = DPPF(CTRL, x[n_]);                                      \
    _Pragma("unroll") for (int n_ = 0; n_ < 8; ++n_)                      \
        x[n_] = fmaf(EXP2(A2[n_] * ss), xp_[n_], x[n_]);                  \
    ss += ssp_;                                                           \
} while (0)

// ---------------------------------------------------------------------------
// Transform B,C into scan layout (chunk length 16), k-contiguous:
//   Bs[b*4096 + i*256 + cg*4 + k] = float4 { B[b][4k+q][cg*16+i] } q=0..3
// Scan thread (h,c,W) reads k=2h,2h+1 at cg=W*32+c -> adjacent 32 B.
// ---------------------------------------------------------------------------
__global__ __launch_bounds__(256) void transform_bc_kernel(
    const float* __restrict__ B_g, const float* __restrict__ C_g,
    float4* __restrict__ Bs, float4* __restrict__ Cs)
{
    const int o = threadIdx.x + 256 * blockIdx.x;   // 4096 float4 per (b, src)
    const int b = blockIdx.y;
    const float* __restrict__ src = blockIdx.z ? C_g : B_g;
    float4* __restrict__ dst = blockIdx.z ? Cs : Bs;
    const int k = o & 3, cg = (o >> 2) & 63, i = o >> 8;
    const int l = cg * CL + i;
    float4 v;
    v.x = src[(size_t)(b * N + 4 * k + 0) * L + l];
    v.y = src[(size_t)(b * N + 4 * k + 1) * L + l];
    v.z = src[(size_t)(b * N + 4 * k + 2) * L + l];
    v.w = src[(size_t)(b * N + 4 * k + 3) * L + l];
    dst[(size_t)b * 4096 + o] = v;
}

// ---------------------------------------------------------------------------
// Scan kernel. 4 waves/block = 2 rows x 2 waves. Wave handles 32 chunks of 16
// steps. lane = h*32 + c: h = n-half (8 states), c = chunk-in-wave.
// Global chunk cg = W*32 + c. Per-thread state: x[8], A2[8], scalar ss.
// ---------------------------------------------------------------------------
template<bool XF>
__global__ __launch_bounds__(TPB) void mamba_scan14_kernel(
    const float* __restrict__ u_g, const float* __restrict__ delta_g,
    const float* __restrict__ A_g,
    const float* __restrict__ B_g, const float* __restrict__ C_g,
    const float4* __restrict__ Bs, const float4* __restrict__ Cs,
    const float* __restrict__ D_g, const float* __restrict__ z_g,
    const float* __restrict__ bias_g, const int* __restrict__ sp_g,
    float* __restrict__ y_g)
{
    __shared__ float2 du_s[RPB * LROW2];  // [r][i*65+cg] = (dtp,u); .x later y_core
    __shared__ float xw_s[RPB][16];       // wave0 segment totals per n

    const int tid = threadIdx.x;
    const int r = tid >> 6;                    // wave id 0..3
    const int lane = tid & 63;
    const int W = r & 1;                       // wave-in-row
    const int rl = r >> 1;                     // local row
    const int h = lane >> 5;                   // n-half: states h*8 .. h*8+7
    const int c = lane & 31;                   // chunk-in-wave
    const int cg = W * 32 + c;                 // global chunk 0..63
    const int row = blockIdx.x * RPB + rl;
    const int b = row >> 11;                   // row / Dm (blocks never straddle)
    const int d = row & (Dm - 1);
    const int sp = sp_g[0];
    const float bias = bias_g[d];
    const int lb = rl * LROW2;
    const int t128 = tid & 127;                // thread-in-row (2 waves)

    // ---- Phase 0: coalesced load of delta/u -> step-major packed LDS ----
#pragma unroll
    for (int p = 0; p < 2; ++p) {
        const int l0 = 4 * t128 + 512 * p;
        const size_t gb = (size_t)row * L + l0;
        const float4 d4 = *reinterpret_cast<const float4*>(&delta_g[gb]);
        const float4 u4 = *reinterpret_cast<const float4*>(&u_g[gb]);
        const float dv[4] = {d4.x, d4.y, d4.z, d4.w};
        const float uv[4] = {u4.x, u4.y, u4.z, u4.w};
#pragma unroll
        for (int k = 0; k < 4; ++k) {
            const int li = l0 + k;
            const float t = dv[k] + bias;
            // softplus: max(t,0) + ln(1 + 2^(-|t|*log2e))
            const float e = EXP2(-fabsf(t) * LOG2E);
            const float p_ = sp ? (fmaxf(t, 0.f) +
                                   __builtin_amdgcn_logf(1.f + e) * RLOG2E)
                                : t;
            const int a = (li & (CL - 1)) * ISTR2 + (li >> 4);  // [step][chunk]
            du_s[lb + a] = make_float2(p_, uv[k]);
        }
    }
    __syncthreads();

    float A2[8];
#pragma unroll
    for (int g = 0; g < 2; ++g) {
        const float4 a4 = *reinterpret_cast<const float4*>(&A_g[d * N + h * 8 + g * 4]);
        A2[g * 4 + 0] = a4.x * LOG2E; A2[g * 4 + 1] = a4.y * LOG2E;
        A2[g * 4 + 2] = a4.z * LOG2E; A2[g * 4 + 3] = a4.w * LOG2E;
    }
    const size_t Bb = (size_t)b * 4096;        // float4 units
    const int k0 = 2 * h;                      // my first n-quad
    const size_t base = Bb + cg * 4 + k0;      // step i lives at base + i*256

    // ---- Pass 1: chunk-local zero-init scan, depth-4 B prefetch ring ----
    float x[8];
#pragma unroll
    for (int n = 0; n < 8; ++n) x[n] = 0.f;
    float ss = 0.f;                            // chunk dtp-sum, then scan prefix

    if (XF) {
        float4 rb0[4], rb1[4];
#pragma unroll
        for (int i = 0; i < 4; ++i) {
            rb0[i] = Bs[base + i * 256];
            rb1[i] = Bs[base + i * 256 + 1];
        }
#pragma unroll
        for (int i = 0; i < CL; ++i) {
            const float2 du = du_s[lb + i * ISTR2 + cg];
            const float dtp = du.x;
            const float dtu = du.x * du.y;
            ss += dtp;
            const float4 B0 = rb0[i & 3];
            const float4 B1 = rb1[i & 3];
            if (i + 4 < CL) {
                rb0[i & 3] = Bs[base + (i + 4) * 256];
                rb1[i & 3] = Bs[base + (i + 4) * 256 + 1];
            }
            const float bv[8] = {B0.x, B0.y, B0.z, B0.w, B1.x, B1.y, B1.z, B1.w};
#pragma unroll
            for (int n = 0; n < 8; ++n) {
                const float a = EXP2(dtp * A2[n]);
                x[n] = fmaf(a, x[n], dtu * bv[n]);
            }
        }
    } else {
#pragma unroll 4
        for (int i = 0; i < CL; ++i) {
            const float2 du = du_s[lb + i * ISTR2 + cg];
            const float dtp = du.x;
            const float dtu = du.x * du.y;
            ss += dtp;
            const int l = cg * CL + i;
            float4 B0, B1;
#pragma unroll
            for (int q = 0; q < 4; ++q) {
                (&B0.x)[q] = B_g[(size_t)(b * N + 4 * k0 + q) * L + l];
                (&B1.x)[q] = B_g[(size_t)(b * N + 4 * k0 + 4 + q) * L + l];
            }
            const float bv[8] = {B0.x, B0.y, B0.z, B0.w, B1.x, B1.y, B1.z, B1.w};
#pragma unroll
            for (int n = 0; n < 8; ++n) {
                const float a = EXP2(dtp * A2[n]);
                x[n] = fmaf(a, x[n], dtu * bv[n]);
            }
        }
    }

    // ---- Combine level 1: 32-lane segmented affine scan via DPP ----
    // After: x[n] = inclusive chunk-combine over [seg_start..c];
    //        ss   = inclusive dtp-prefix over the same window.
    COMBINE_STAGE(0x111);   // row_shr:1
    COMBINE_STAGE(0x112);   // row_shr:2
    COMBINE_STAGE(0x114);   // row_shr:4
    COMBINE_STAGE(0x118);   // row_shr:8
    COMBINE_STAGE(0x142);   // row_bcast:15 (cross-row fix within 32-segment)

    // ---- Combine level 2: cross-wave. Wave0 publishes its row-half totals.
    if (W == 0 && c == 31) {
#pragma unroll
        for (int n = 0; n < 8; ++n) xw_s[rl][h * 8 + n] = x[n];
    }
    __syncthreads();

    // exclusive shift within segment (+wave1 prepends wave0's total).
    // exclusive(c) = inclusive(c-1): row_shr:1, except c==16 which needs
    // lane15/47 -> row_bcast:15. c==0 lanes correctly get 0.
    float xt[8];
#pragma unroll
    for (int n = 0; n < 8; ++n) xt[n] = xw_s[rl][h * 8 + n];
    {
        const float ss1 = DPPF(0x111, ss);
        const float ssb = DPPF(0x142, ss);
        const float ssx = (c == 16) ? ssb : ss1;
#pragma unroll
        for (int n = 0; n < 8; ++n) {
            const float x1 = DPPF(0x111, x[n]);
            const float xb = DPPF(0x142, x[n]);
            const float xe = (c == 16) ? xb : x1;
            // wave1: prepend wave0 total through this chunk's exclusive decay
            x[n] = W ? fmaf(EXP2(A2[n] * ssx), xt[n], xe) : xe;
        }
    }

    // ---- Pass 2: rescan with init states; y_core -> du_s[.].x ----
    const float Dd = D_g[d];
    if (XF) {
        float4 rb0[4], rb1[4], rc0[4], rc1[4];
#pragma unroll
        for (int i = 0; i < 4; ++i) {
            rb0[i] = Bs[base + i * 256];
            rb1[i] = Bs[base + i * 256 + 1];
            rc0[i] = Cs[base + i * 256];
            rc1[i] = Cs[base + i * 256 + 1];
        }
#pragma unroll
        for (int i = 0; i < CL; ++i) {
            const float2 du = du_s[lb + i * ISTR2 + cg];
            const float dtp = du.x;
            const float uu = du.y;
            const float dtu = dtp * uu;
            const float4 B0 = rb0[i & 3], B1 = rb1[i & 3];
            const float4 C0 = rc0[i & 3], C1 = rc1[i & 3];
            if (i + 4 < CL) {
                rb0[i & 3] = Bs[base + (i + 4) * 256];
                rb1[i & 3] = Bs[base + (i + 4) * 256 + 1];
                rc0[i & 3] = Cs[base + (i + 4) * 256];
                rc1[i & 3] = Cs[base + (i + 4) * 256 + 1];
            }
            const float bv[8] = {B0.x, B0.y, B0.z, B0.w, B1.x, B1.y, B1.z, B1.w};
            const float cv[8] = {C0.x, C0.y, C0.z, C0.w, C1.x, C1.y, C1.z, C1.w};
            float acc = 0.f;
#pragma unroll
            for (int n = 0; n < 8; ++n) {
                const float a = EXP2(dtp * A2[n]);
                x[n] = fmaf(a, x[n], dtu * bv[n]);
                acc = fmaf(x[n], cv[n], acc);
            }
            acc += __shfl_xor(acc, 32, 64);        // sum the two n-halves
            if (h == 0)
                du_s[lb + i * ISTR2 + cg].x = fmaf(uu, Dd, acc);   // y_core
        }
    } else {
#pragma unroll 4
        for (int i = 0; i < CL; ++i) {
            const float2 du = du_s[lb + i * ISTR2 + cg];
            const float dtp = du.x;
            const float uu = du.y;
            const float dtu = dtp * uu;
            const int l = cg * CL + i;
            float4 B0, B1, C0, C1;
#pragma unroll
            for (int q = 0; q < 4; ++q) {
                (&B0.x)[q] = B_g[(size_t)(b * N + 4 * k0 + q) * L + l];
                (&B1.x)[q] = B_g[(size_t)(b * N + 4 * k0 + 4 + q) * L + l];
                (&C0.x)[q] = C_g[(size_t)(b * N + 4 * k0 + q) * L + l];
                (&C1.x)[q] = C_g[(size_t)(b * N + 4 * k0 + 4 + q) * L + l];
            }
            const float bv[8] = {B0.x, B0.y, B0.z, B0.w, B1.x, B1.y, B1.z, B1.w};
            const float cv[8] = {C0.x, C0.y, C0.z, C0.w, C1.x, C1.y, C1.z, C1.w};
            float acc = 0.f;
#pragma unroll
            for (int n = 0; n < 8; ++n) {
                const float a = EXP2(dtp * A2[n]);
                x[n] = fmaf(a, x[n], dtu * bv[n]);
                acc = fmaf(x[n], cv[n], acc);
            }
            acc += __shfl_xor(acc, 32, 64);
            if (h == 0)
                du_s[lb + i * ISTR2 + cg].x = fmaf(uu, Dd, acc);
        }
    }
    __syncthreads();

    // ---- Epilogue: coalesced z read, silu gate, coalesced y store ----
#pragma unroll
    for (int p = 0; p < 2; ++p) {
        const int l0 = 4 * t128 + 512 * p;
        const size_t gb = (size_t)row * L + l0;
        const float4 z4 = *reinterpret_cast<const float4*>(&z_g[gb]);
        const float zv[4] = {z4.x, z4.y, z4.z, z4.w};
        float out[4];
#pragma unroll
        for (int k = 0; k < 4; ++k) {
            const int li = l0 + k;
            const float yc = du_s[lb + (li & (CL - 1)) * ISTR2 + (li >> 4)].x;
            const float e = EXP2(-zv[k] * LOG2E);
            const float sig = __builtin_amdgcn_rcpf(1.f + e);
            out[k] = yc * (zv[k] * sig);
        }
        *reinterpret_cast<float4*>(&y_g[gb]) = make_float4(out[0], out[1], out[2], out[3]);
    }
}

extern "C" void kernel_launch(void* const* d_in, const int* in_sizes, int n_in,
                              void* d_out, int out_size, void* d_ws, size_t ws_size,
                              hipStream_t stream) {
    const float* u     = (const float*)d_in[0];
    const float* delta = (const float*)d_in[1];
    const float* A     = (const float*)d_in[2];
    const float* B     = (const float*)d_in[3];
    const float* C     = (const float*)d_in[4];
    const float* D     = (const float*)d_in[5];
    const float* z     = (const float*)d_in[6];
    const float* bias  = (const float*)d_in[7];
    const int*   sp    = (const int*)d_in[8];
    float* y = (float*)d_out;

    const size_t bc_bytes = (size_t)Bsz * 4096 * sizeof(float4);  // 128 KB each
    const bool xf = ws_size >= 2 * bc_bytes;
    float4* Bs = (float4*)d_ws;
    float4* Cs = (float4*)((char*)d_ws + bc_bytes);

    if (xf) {
        transform_bc_kernel<<<dim3(16, Bsz, 2), 256, 0, stream>>>(B, C, Bs, Cs);
        mamba_scan14_kernel<true><<<dim3((Bsz * Dm) / RPB), TPB, 0, stream>>>(
            u, delta, A, B, C, Bs, Cs, D, z, bias, sp, y);
    } else {
        mamba_scan14_kernel<false><<<dim3((Bsz * Dm) / RPB), TPB, 0, stream>>>(
            u, delta, A, B, C, Bs, Cs, D, z, bias, sp, y);
    }
}